// Round 4
// baseline (174.273 us; speedup 1.0000x reference)
//
#include <hip/hip_runtime.h>
#include <hip/hip_bf16.h>
#include <stdint.h>

typedef __bf16 bf16x8 __attribute__((ext_vector_type(8)));
typedef float f32x4 __attribute__((ext_vector_type(4)));

#define NQ 8192
#define NP 4096
#define DD 512

// Fused pairwise-distance kernel: out[n][m] = (||x_n||^2 + ||y_m||^2 - 2 x.y)/512
// 256x256 tile per block, BK=64 (2 K-halves), 8 waves (4M x 2N, each 64x128).
// fp32 inputs staged global->reg->(cvt bf16 + fp32 norm accumulate)->ds_write,
// 2-phase load->write gap; all waitcnts compiler-derived (register-visible deps).
// LDS: A [buf][ks][256r][32c] bf16 at 0, B same at +64KB; XOR-16B-chunk swizzle
// keyed by (row>>1)&3, both sides (write addr linear P, source L(P); reads use
// cswz). 4 phases per K-tile: (ks, n-half) quadrants, 16 MFMA each; fragment
// ping-pong (a0/a1, bA/bB) read one phase ahead. Norm rows fixed per
// (wave, chunk, lane); wrapped tail stages gated out of the accumulation.
__global__ __launch_bounds__(512, 2) void fused_dist_kernel(
    const float* __restrict__ X, const float* __restrict__ Y,
    float* __restrict__ out) {
  __shared__ __align__(128) unsigned char lds[133120];
  float* xs_l = (float*)(lds + 131072);
  float* ys_l = (float*)(lds + 131072 + 1024);

  const int tid = threadIdx.x;
  const int wave = tid >> 6;
  const int lane = tid & 63;
  const int fr = lane & 15, fq = lane >> 4;
  const int wr = wave >> 1;  // 0..3: rows wr*64..+64
  const int wc = wave & 1;   // 0..1: cols wc*128..+128

  // XCD swizzle (512 blocks, 64 per XCD, bijective).
  const int bid = blockIdx.x;
  const int wgid = (bid & 7) * 64 + (bid >> 3);
  const int tileN = wgid & 15;
  const int tileM = wgid >> 4;
  const int brow = tileM * 256;
  const int bcol = tileN * 256;

  // Staging geometry: chunk i dst byte P_i (linear), source col from L(P_i).
  const unsigned Pw0 = (unsigned)(wave * 2) * 1024u + (unsigned)lane * 16u;
  const unsigned Pw1 = Pw0 + 1024u;
  const unsigned L0 = Pw0 ^ (((Pw0 >> 7) & 3u) << 4);
  const unsigned L1 = Pw1 ^ (((Pw1 >> 7) & 3u) << 4);
  const unsigned srow0 = L0 >> 6, scol0 = (L0 & 63u) >> 1;
  const unsigned srow1 = L1 >> 6, scol1 = (L1 & 63u) >> 1;
  const unsigned aoff0 = (unsigned)(brow + (int)srow0) * DD + scol0;
  const unsigned aoff1 = (unsigned)(brow + (int)srow1) * DD + scol1;
  const unsigned boff0 = (unsigned)(bcol + (int)srow0) * DD + scol0;
  const unsigned boff1 = (unsigned)(bcol + (int)srow1) * DD + scol1;

  // Fragment read offsets (swizzled).
  const unsigned cswz = (unsigned)((fq ^ ((fr >> 1) & 3)) << 4);
  const unsigned rA = (unsigned)((wr * 64 + fr) * 64) + cswz;
  const unsigned rB = (unsigned)((wc * 128 + fr) * 64) + cswz;

#define REG_A(buf, ks) ((unsigned)((buf)*32768 + (ks)*16384))
#define REG_B(buf, ks) ((unsigned)(65536 + (buf)*32768 + (ks)*16384))

  f32x4 acc[4][8] = {};
  bf16x8 a0[4], a1[4], bA[4], bB[4];
  float4 s0a, s0b, s0c, s0d, s1a, s1b, s1c, s1d;
  float nA0 = 0.f, nA1 = 0.f, nB0 = 0.f, nB1 = 0.f;

  auto issueX = [&](float4& c0, float4& c1, float4& c2, float4& c3, int t, int ks) {
    const unsigned kofs = (unsigned)((t & 7) * 64 + ks * 32);
    const float* p0 = X + aoff0 + kofs;
    const float* p1 = X + aoff1 + kofs;
    c0 = *(const float4*)p0; c1 = *(const float4*)(p0 + 4);
    c2 = *(const float4*)p1; c3 = *(const float4*)(p1 + 4);
  };
  auto issueY = [&](float4& c0, float4& c1, float4& c2, float4& c3, int t, int ks) {
    const unsigned kofs = (unsigned)((t & 7) * 64 + ks * 32);
    const float* p0 = Y + boff0 + kofs;
    const float* p1 = Y + boff1 + kofs;
    c0 = *(const float4*)p0; c1 = *(const float4*)(p0 + 4);
    c2 = *(const float4*)p1; c3 = *(const float4*)(p1 + 4);
  };

  auto drain = [&](const float4& c0, const float4& c1, const float4& c2,
                   const float4& c3, unsigned rbase, float gate, float& n0,
                   float& n1) {
    n0 += gate * (c0.x*c0.x + c0.y*c0.y + c0.z*c0.z + c0.w*c0.w +
                  c1.x*c1.x + c1.y*c1.y + c1.z*c1.z + c1.w*c1.w);
    n1 += gate * (c2.x*c2.x + c2.y*c2.y + c2.z*c2.z + c2.w*c2.w +
                  c3.x*c3.x + c3.y*c3.y + c3.z*c3.z + c3.w*c3.w);
    bf16x8 w0, w1;
    w0[0]=(__bf16)c0.x; w0[1]=(__bf16)c0.y; w0[2]=(__bf16)c0.z; w0[3]=(__bf16)c0.w;
    w0[4]=(__bf16)c1.x; w0[5]=(__bf16)c1.y; w0[6]=(__bf16)c1.z; w0[7]=(__bf16)c1.w;
    w1[0]=(__bf16)c2.x; w1[1]=(__bf16)c2.y; w1[2]=(__bf16)c2.z; w1[3]=(__bf16)c2.w;
    w1[4]=(__bf16)c3.x; w1[5]=(__bf16)c3.y; w1[6]=(__bf16)c3.z; w1[7]=(__bf16)c3.w;
    *(bf16x8*)(lds + rbase + Pw0) = w0;
    *(bf16x8*)(lds + rbase + Pw1) = w1;
  };

  auto readA4 = [&](bf16x8* d, unsigned base) {
    #pragma unroll
    for (int m = 0; m < 4; ++m)
      d[m] = *(const bf16x8*)(lds + base + rA + (unsigned)m * 1024u);
  };
  auto readB4 = [&](bf16x8* d, unsigned base, int nh) {
    #pragma unroll
    for (int n = 0; n < 4; ++n)
      d[n] = *(const bf16x8*)(lds + base + rB + (unsigned)(nh * 4 + n) * 1024u);
  };
  auto mfma44 = [&](const bf16x8* aa, const bf16x8* bb, int nb) {
    #pragma unroll
    for (int m = 0; m < 4; ++m)
      #pragma unroll
      for (int n = 0; n < 4; ++n)
        acc[m][nb + n] = __builtin_amdgcn_mfma_f32_16x16x32_bf16(
            aa[m], bb[n], acc[m][nb + n], 0, 0, 0);
  };

  // ---- prologue: software-pipelined stage of tiles 0,1 + W1=B1(1), W2=A0(2)
  issueX(s0a,s0b,s0c,s0d, 0, 0);                       // S1 = A0(0)
  issueY(s1a,s1b,s1c,s1d, 0, 0);                       // S2 = B0(0)
  drain(s0a,s0b,s0c,s0d, REG_A(0,0), 1.f, nA0, nA1);   // S1
  issueX(s0a,s0b,s0c,s0d, 0, 1);                       // S3 = A1(0)
  drain(s1a,s1b,s1c,s1d, REG_B(0,0), 1.f, nB0, nB1);   // S2
  issueY(s1a,s1b,s1c,s1d, 0, 1);                       // S4 = B1(0)
  drain(s0a,s0b,s0c,s0d, REG_A(0,1), 1.f, nA0, nA1);   // S3
  issueX(s0a,s0b,s0c,s0d, 1, 0);                       // S5 = A0(1)
  drain(s1a,s1b,s1c,s1d, REG_B(0,1), 1.f, nB0, nB1);   // S4
  issueY(s1a,s1b,s1c,s1d, 1, 0);                       // S6 = B0(1)
  drain(s0a,s0b,s0c,s0d, REG_A(1,0), 1.f, nA0, nA1);   // S5
  issueX(s0a,s0b,s0c,s0d, 1, 1);                       // S7 = A1(1)
  drain(s1a,s1b,s1c,s1d, REG_B(1,0), 1.f, nB0, nB1);   // S6
  issueY(s1a,s1b,s1c,s1d, 1, 1);                       // W1 = B1(1) (in flight)
  drain(s0a,s0b,s0c,s0d, REG_A(1,1), 1.f, nA0, nA1);   // S7
  issueX(s0a,s0b,s0c,s0d, 2, 0);                       // W2 = A0(2) (in flight)
  asm volatile("s_waitcnt lgkmcnt(0)" ::: "memory");
  __builtin_amdgcn_s_barrier();

  readA4(a0, REG_A(0, 0));
  readB4(bA, REG_B(0, 0), 0);

  #pragma unroll 2
  for (int g = 0; g < 8; ++g) {
    const int buf = g & 1;
    const float g1 = (g + 1 < 8) ? 1.0f : 0.0f;
    const float g2 = (g + 2 < 8) ? 1.0f : 0.0f;

    // ---- Ph1: MFMA(a0, bA -> acc[:,0..3]) ----
    drain(s1a,s1b,s1c,s1d, REG_B(buf ^ 1, 1), g1, nB0, nB1);  // B1(g+1)
    issueY(s1a,s1b,s1c,s1d, g + 2, 0);                        // B0(g+2)
    readB4(bB, REG_B(buf, 0), 1);
    __builtin_amdgcn_s_barrier();
    __builtin_amdgcn_sched_barrier(0);
    __builtin_amdgcn_s_setprio(1);
    mfma44(a0, bA, 0);
    __builtin_amdgcn_s_setprio(0);
    __builtin_amdgcn_sched_barrier(0);
    __builtin_amdgcn_s_barrier();

    // ---- Ph2: MFMA(a0, bB -> acc[:,4..7]) ----
    drain(s0a,s0b,s0c,s0d, REG_A(buf, 0), g2, nA0, nA1);      // A0(g+2)
    issueX(s0a,s0b,s0c,s0d, g + 2, 1);                        // A1(g+2)
    readA4(a1, REG_A(buf, 1));
    readB4(bA, REG_B(buf, 1), 0);
    __builtin_amdgcn_s_barrier();
    __builtin_amdgcn_sched_barrier(0);
    __builtin_amdgcn_s_setprio(1);
    mfma44(a0, bB, 4);
    __builtin_amdgcn_s_setprio(0);
    __builtin_amdgcn_sched_barrier(0);
    __builtin_amdgcn_s_barrier();

    // ---- Ph3: MFMA(a1, bA -> acc[:,0..3]) ----
    drain(s1a,s1b,s1c,s1d, REG_B(buf, 0), g2, nB0, nB1);      // B0(g+2)
    issueY(s1a,s1b,s1c,s1d, g + 2, 1);                        // B1(g+2)
    readB4(bB, REG_B(buf, 1), 1);
    __builtin_amdgcn_s_barrier();
    __builtin_amdgcn_sched_barrier(0);
    __builtin_amdgcn_s_setprio(1);
    mfma44(a1, bA, 0);
    __builtin_amdgcn_s_setprio(0);
    __builtin_amdgcn_sched_barrier(0);
    __builtin_amdgcn_s_barrier();

    // ---- Ph4: MFMA(a1, bB -> acc[:,4..7]) ----
    drain(s0a,s0b,s0c,s0d, REG_A(buf, 1), g2, nA0, nA1);      // A1(g+2)
    issueX(s0a,s0b,s0c,s0d, g + 3, 0);                        // A0(g+3)
    readA4(a0, REG_A(buf ^ 1, 0));
    readB4(bA, REG_B(buf ^ 1, 0), 0);
    __builtin_amdgcn_s_barrier();
    __builtin_amdgcn_sched_barrier(0);
    __builtin_amdgcn_s_setprio(1);
    mfma44(a1, bB, 4);
    __builtin_amdgcn_s_setprio(0);
    __builtin_amdgcn_sched_barrier(0);
    __builtin_amdgcn_s_barrier();
  }

  // ---- norms: reduce across 4-lane row groups, publish via LDS ----
  nA0 += __shfl_xor(nA0, 1, 64); nA0 += __shfl_xor(nA0, 2, 64);
  nA1 += __shfl_xor(nA1, 1, 64); nA1 += __shfl_xor(nA1, 2, 64);
  nB0 += __shfl_xor(nB0, 1, 64); nB0 += __shfl_xor(nB0, 2, 64);
  nB1 += __shfl_xor(nB1, 1, 64); nB1 += __shfl_xor(nB1, 2, 64);
  if ((lane & 3) == 0) {
    const int r0 = wave * 32 + (lane >> 2);
    xs_l[r0] = nA0; xs_l[r0 + 16] = nA1;
    ys_l[r0] = nB0; ys_l[r0 + 16] = nB1;
  }
  asm volatile("s_waitcnt lgkmcnt(0)" ::: "memory");
  __builtin_amdgcn_s_barrier();

  // ---- epilogue: out = (||x||^2 + ||y||^2 - 2*dot) / 512 ----
  float ysv[8];
  #pragma unroll
  for (int n = 0; n < 8; ++n) ysv[n] = ys_l[wc * 128 + n * 16 + fr];
  #pragma unroll
  for (int m = 0; m < 4; ++m) {
    const int rl = wr * 64 + m * 16 + fq * 4;
    const f32x4 xv = *(const f32x4*)(xs_l + rl);
    #pragma unroll
    for (int n = 0; n < 8; ++n) {
      const int col = bcol + wc * 128 + n * 16 + fr;
      #pragma unroll
      for (int r = 0; r < 4; ++r) {
        out[(size_t)(brow + rl + r) * NP + col] =
            (xv[r] + ysv[n] - 2.0f * acc[m][n][r]) * (1.0f / 512.0f);
      }
    }
  }
}

extern "C" void kernel_launch(void* const* d_in, const int* in_sizes, int n_in,
                              void* d_out, int out_size, void* d_ws, size_t ws_size,
                              hipStream_t stream) {
  const float* X = (const float*)d_in[0];  // z_queries (8192, 512)
  const float* Y = (const float*)d_in[1];  // class_prototypes (4096, 512)
  float* out = (float*)d_out;              // (8192, 4096)
  fused_dist_kernel<<<512, 512, 0, stream>>>(X, Y, out);
}

// Round 5
// 70.347 us; speedup vs baseline: 2.4774x; 2.4774x over previous
//
#include <hip/hip_runtime.h>
#include <hip/hip_bf16.h>
#include <stdint.h>

typedef __bf16 bf16x8 __attribute__((ext_vector_type(8)));
typedef float f32x4 __attribute__((ext_vector_type(4)));
typedef unsigned short ushort8 __attribute__((ext_vector_type(8)));

#define NQ 8192
#define NP 4096
#define DD 512
#define NTILES 8  // DD / 64

__device__ inline unsigned short f32_to_bf16_rne(float f) {
  union { float f; uint32_t u; } v; v.f = f;
  uint32_t u = v.u;
  return (unsigned short)((u + 0x7fffu + ((u >> 16) & 1u)) >> 16);
}

// One wave per row: fp32 -> bf16 copy + fp32 sum-of-squares per row.
__global__ __launch_bounds__(256) void cvt_norms_kernel(
    const float* __restrict__ X, const float* __restrict__ Y,
    unsigned short* __restrict__ Xb, unsigned short* __restrict__ Yb,
    float* __restrict__ xsq, float* __restrict__ ysq) {
  const int wave = threadIdx.x >> 6;
  const int lane = threadIdx.x & 63;
  const int row = blockIdx.x * 4 + wave;  // 0..12287

  const float* src;
  unsigned short* dst;
  float* nrm;
  if (row < NQ) {
    src = X + (size_t)row * DD;
    dst = Xb + (size_t)row * DD;
    nrm = xsq + row;
  } else {
    const int r = row - NQ;
    src = Y + (size_t)r * DD;
    dst = Yb + (size_t)r * DD;
    nrm = ysq + r;
  }

  const float4 v0 = *(const float4*)(src + lane * 8);
  const float4 v1 = *(const float4*)(src + lane * 8 + 4);
  float s = v0.x * v0.x + v0.y * v0.y + v0.z * v0.z + v0.w * v0.w +
            v1.x * v1.x + v1.y * v1.y + v1.z * v1.z + v1.w * v1.w;

  ushort8 o;
  o[0] = f32_to_bf16_rne(v0.x);
  o[1] = f32_to_bf16_rne(v0.y);
  o[2] = f32_to_bf16_rne(v0.z);
  o[3] = f32_to_bf16_rne(v0.w);
  o[4] = f32_to_bf16_rne(v1.x);
  o[5] = f32_to_bf16_rne(v1.y);
  o[6] = f32_to_bf16_rne(v1.z);
  o[7] = f32_to_bf16_rne(v1.w);
  *(ushort8*)(dst + lane * 8) = o;

  #pragma unroll
  for (int off = 32; off; off >>= 1) s += __shfl_xor(s, off, 64);
  if (lane == 0) *nrm = s;
}

// ---------------------------------------------------------------------------
// 128x256-tile NT GEMM (C = Xb * Yb^T), BK=64, 8 waves (2M x 4N, each 64x64),
// r2-style 4-phase schedule, global_load_lds staging, fused distance epilogue.
// 1024 blocks = 4 rounds/CU: small per-round write tails overlap the next
// block's compute (the r2 512-block version exposed ~21 us of store tail).
//
// LDS (96 KiB): A [buf][ks][128r][32c] bf16: REG_A = buf*16384 + ks*8192.
//               B [buf][ks][256r][32c]:      REG_B = 32768 + buf*32768 + ks*16384.
// Swizzle: 16B-chunk XOR keyed by (row>>1)&3, both sides (linear LDS dst,
// inverse-swizzled global src; reads add cswz).
//
// Ledger (loads/thread: A-stage=1, B-stage=2; prologue 10; +6/tile):
//   stages: Ph1 -> B1(g+1), Ph2 -> A0(g+2), Ph3 -> B0(g+2), Ph4 -> A1(g+2)
//   vmcnt(7) at Ph2/Ph4 pre-MFMA barrier and prologue:
//     Ph4(g-1): issued 6g+10, certifies A0(g) E=6g+1, B0(g) E=6g+3  (<=7) ok
//     Ph2(g):   issued 6g+13, certifies A1(g) E=6g+4, B1(g) E=6g+6  (<=7) ok
//   WAR: each region's last readers drain (lgkm(0) + end barrier) before its
//   re-stage issue one tile early (2-buffer in-place discipline, as r2).
// ---------------------------------------------------------------------------
__global__ __launch_bounds__(512, 2) void dist_gemm_kernel(
    const unsigned short* __restrict__ Xb, const unsigned short* __restrict__ Yb,
    const float* __restrict__ xsq, const float* __restrict__ ysq,
    float* __restrict__ out) {
  __shared__ __align__(128) unsigned char lds[98304];

  const int tid = threadIdx.x;
  const int wave = tid >> 6;
  const int lane = tid & 63;
  const int fr = lane & 15, fq = lane >> 4;
  const int wr = wave & 1;   // 0..1: rows wr*64..+64
  const int wc = wave >> 1;  // 0..3: cols wc*64..+64

  // XCD swizzle: 1024 blocks, 128 contiguous wgids per XCD (bijective).
  const int bid = blockIdx.x;
  const int wgid = (bid & 7) * 128 + (bid >> 3);
  const int tileN = wgid & 15;   // 16 N-tiles (256 cols)
  const int tileM = wgid >> 4;   // 64 M-tiles (128 rows)
  const int brow = tileM * 128;
  const int bcol = tileN * 256;

#define REG_A(buf, ks) ((unsigned)((buf)*16384 + (ks)*8192))
#define REG_B(buf, ks) ((unsigned)(32768 + (buf)*32768 + (ks)*16384))

  // A half-tile: 8 KB, 1 load/thread.
  auto stageA = [&](int buf, int t, int ks) {
    const unsigned P0 = (unsigned)wave * 1024u;
    const unsigned P = P0 + (unsigned)lane * 16u;
    const unsigned L = P ^ (((P >> 7) & 3u) << 4);
    const unsigned row = L >> 6;
    const unsigned col = (L & 63u) >> 1;
    const unsigned short* src =
        Xb + (size_t)(brow + (int)row) * DD + (t & 7) * 64 + ks * 32 + col;
    __builtin_amdgcn_global_load_lds(
        (const __attribute__((address_space(1))) void*)src,
        (__attribute__((address_space(3))) void*)(lds + REG_A(buf, ks) + P0),
        16, 0, 0);
  };
  // B half-tile: 16 KB, 2 loads/thread.
  auto stageB = [&](int buf, int t, int ks) {
    #pragma unroll
    for (int i = 0; i < 2; ++i) {
      const unsigned P0 = (unsigned)(wave * 2 + i) * 1024u;
      const unsigned P = P0 + (unsigned)lane * 16u;
      const unsigned L = P ^ (((P >> 7) & 3u) << 4);
      const unsigned row = L >> 6;
      const unsigned col = (L & 63u) >> 1;
      const unsigned short* src =
          Yb + (size_t)(bcol + (int)row) * DD + (t & 7) * 64 + ks * 32 + col;
      __builtin_amdgcn_global_load_lds(
          (const __attribute__((address_space(1))) void*)src,
          (__attribute__((address_space(3))) void*)(lds + REG_B(buf, ks) + P0),
          16, 0, 0);
    }
  };

  // fragment read offsets (swizzled)
  const unsigned cswz = (unsigned)((fq ^ ((fr >> 1) & 3)) << 4);
  const unsigned rA = (unsigned)((wr * 64 + fr) * 64) + cswz;  // + m*1024
  const unsigned rB = (unsigned)((wc * 64 + fr) * 64) + cswz;  // + n*1024

  f32x4 acc[4][4] = {};
  bf16x8 a[4], b0, b1, b2, b3;

  // ---- prologue: A0(0) B0(0) A1(0) B1(0) A0(1) B0(1) A1(1) = 10 loads ----
  stageA(0, 0, 0);
  stageB(0, 0, 0);
  stageA(0, 0, 1);
  stageB(0, 0, 1);
  stageA(1, 1, 0);
  stageB(1, 1, 0);
  stageA(1, 1, 1);
  asm volatile("s_waitcnt vmcnt(7)" ::: "memory");
  __builtin_amdgcn_s_barrier();

  #pragma unroll 2
  for (int g = 0; g < NTILES; ++g) {
    const int buf = g & 1;

    // ---- Ph1: ks=0, n 0..1 ----
    #pragma unroll
    for (int m = 0; m < 4; ++m)
      a[m] = *(const bf16x8*)(lds + REG_A(buf, 0) + rA + (unsigned)m * 1024u);
    b0 = *(const bf16x8*)(lds + REG_B(buf, 0) + rB + 0u);
    b1 = *(const bf16x8*)(lds + REG_B(buf, 0) + rB + 1024u);
    stageB(buf ^ 1, g + 1, 1);  // B1(g+1)
    __builtin_amdgcn_s_barrier();
    asm volatile("s_waitcnt lgkmcnt(0)" ::: "memory");
    __builtin_amdgcn_sched_barrier(0);
    __builtin_amdgcn_s_setprio(1);
    #pragma unroll
    for (int m = 0; m < 4; ++m) {
      acc[m][0] = __builtin_amdgcn_mfma_f32_16x16x32_bf16(a[m], b0, acc[m][0], 0, 0, 0);
      acc[m][1] = __builtin_amdgcn_mfma_f32_16x16x32_bf16(a[m], b1, acc[m][1], 0, 0, 0);
    }
    __builtin_amdgcn_s_setprio(0);
    __builtin_amdgcn_s_barrier();

    // ---- Ph2: ks=0, n 2..3 ----
    b2 = *(const bf16x8*)(lds + REG_B(buf, 0) + rB + 2048u);
    b3 = *(const bf16x8*)(lds + REG_B(buf, 0) + rB + 3072u);
    stageA(buf, g + 2, 0);  // A0(g+2)
    asm volatile("s_waitcnt vmcnt(7)" ::: "memory");
    __builtin_amdgcn_s_barrier();
    asm volatile("s_waitcnt lgkmcnt(0)" ::: "memory");
    __builtin_amdgcn_sched_barrier(0);
    __builtin_amdgcn_s_setprio(1);
    #pragma unroll
    for (int m = 0; m < 4; ++m) {
      acc[m][2] = __builtin_amdgcn_mfma_f32_16x16x32_bf16(a[m], b2, acc[m][2], 0, 0, 0);
      acc[m][3] = __builtin_amdgcn_mfma_f32_16x16x32_bf16(a[m], b3, acc[m][3], 0, 0, 0);
    }
    __builtin_amdgcn_s_setprio(0);
    __builtin_amdgcn_s_barrier();

    // ---- Ph3: ks=1, n 0..1 ----
    #pragma unroll
    for (int m = 0; m < 4; ++m)
      a[m] = *(const bf16x8*)(lds + REG_A(buf, 1) + rA + (unsigned)m * 1024u);
    b0 = *(const bf16x8*)(lds + REG_B(buf, 1) + rB + 0u);
    b1 = *(const bf16x8*)(lds + REG_B(buf, 1) + rB + 1024u);
    stageB(buf, g + 2, 0);  // B0(g+2)
    __builtin_amdgcn_s_barrier();
    asm volatile("s_waitcnt lgkmcnt(0)" ::: "memory");
    __builtin_amdgcn_sched_barrier(0);
    __builtin_amdgcn_s_setprio(1);
    #pragma unroll
    for (int m = 0; m < 4; ++m) {
      acc[m][0] = __builtin_amdgcn_mfma_f32_16x16x32_bf16(a[m], b0, acc[m][0], 0, 0, 0);
      acc[m][1] = __builtin_amdgcn_mfma_f32_16x16x32_bf16(a[m], b1, acc[m][1], 0, 0, 0);
    }
    __builtin_amdgcn_s_setprio(0);
    __builtin_amdgcn_s_barrier();

    // ---- Ph4: ks=1, n 2..3 ----
    b2 = *(const bf16x8*)(lds + REG_B(buf, 1) + rB + 2048u);
    b3 = *(const bf16x8*)(lds + REG_B(buf, 1) + rB + 3072u);
    stageA(buf, g + 2, 1);  // A1(g+2)
    asm volatile("s_waitcnt vmcnt(7)" ::: "memory");
    __builtin_amdgcn_s_barrier();
    asm volatile("s_waitcnt lgkmcnt(0)" ::: "memory");
    __builtin_amdgcn_sched_barrier(0);
    __builtin_amdgcn_s_setprio(1);
    #pragma unroll
    for (int m = 0; m < 4; ++m) {
      acc[m][2] = __builtin_amdgcn_mfma_f32_16x16x32_bf16(a[m], b2, acc[m][2], 0, 0, 0);
      acc[m][3] = __builtin_amdgcn_mfma_f32_16x16x32_bf16(a[m], b3, acc[m][3], 0, 0, 0);
    }
    __builtin_amdgcn_s_setprio(0);
    __builtin_amdgcn_s_barrier();
  }

  // ---- epilogue: out[row][col] = (xsq[row] + ysq[col] - 2*acc) / 512 ----
  float ysv[4];
  #pragma unroll
  for (int n = 0; n < 4; ++n) ysv[n] = ysq[bcol + wc * 64 + n * 16 + fr];

  #pragma unroll
  for (int m = 0; m < 4; ++m) {
    const int rowb = brow + wr * 64 + m * 16 + fq * 4;
    float xsv[4];
    #pragma unroll
    for (int r = 0; r < 4; ++r) xsv[r] = xsq[rowb + r];
    #pragma unroll
    for (int n = 0; n < 4; ++n) {
      const int col = bcol + wc * 64 + n * 16 + fr;
      #pragma unroll
      for (int r = 0; r < 4; ++r) {
        out[(size_t)(rowb + r) * NP + col] =
            (xsv[r] + ysv[n] - 2.0f * acc[m][n][r]) * (1.0f / 512.0f);
      }
    }
  }
}

extern "C" void kernel_launch(void* const* d_in, const int* in_sizes, int n_in,
                              void* d_out, int out_size, void* d_ws, size_t ws_size,
                              hipStream_t stream) {
  const float* X = (const float*)d_in[0];  // z_queries (8192, 512)
  const float* Y = (const float*)d_in[1];  // class_prototypes (4096, 512)
  float* out = (float*)d_out;              // (8192, 4096)

  unsigned short* Xb = (unsigned short*)d_ws;   // 8192*512 bf16
  unsigned short* Yb = Xb + (size_t)NQ * DD;    // 4096*512 bf16
  float* xsq = (float*)(Yb + (size_t)NP * DD);  // 8192 f32
  float* ysq = xsq + NQ;                        // 4096 f32

  cvt_norms_kernel<<<(NQ + NP) / 4, 256, 0, stream>>>(X, Y, Xb, Yb, xsq, ysq);
  dist_gemm_kernel<<<(NQ / 128) * (NP / 256), 512, 0, stream>>>(Xb, Yb, xsq,
                                                                ysq, out);
}